// Round 9
// baseline (1104.809 us; speedup 1.0000x reference)
//
#include <hip/hip_runtime.h>

// Problem constants (match reference)
constexpr int B_    = 4;
constexpr int N_    = 4096;          // rows per batch
constexpr int DIM   = 1024;
constexpr int HEADS = 16;
constexpr int DHEAD = 64;
constexpr int INNER = 1024;          // HEADS*DHEAD
constexpr int QKVN  = 3 * INNER;     // 3072
constexpr float EPS = 1e-5f;

typedef __attribute__((ext_vector_type(8))) short short8v;   // 8 bf16 (4 VGPRs)
typedef __attribute__((ext_vector_type(4))) float float4v;   // MFMA acc

// ---- bf16 split helpers (RNE) ----------------------------------------------
__device__ __forceinline__ unsigned short f2bf(float f) {
    unsigned int u = __float_as_uint(f);
    u += 0x7FFFu + ((u >> 16) & 1u);
    return (unsigned short)(u >> 16);
}
__device__ __forceinline__ float bf2f(unsigned short h) {
    return __uint_as_float((unsigned int)h << 16);
}

// ---------------------------------------------------------------------------
// split_f32: elementwise x -> (hi, lo) bf16 pair.  n4 = elements/4.
// ---------------------------------------------------------------------------
__global__ __launch_bounds__(256)
void split_f32(const float* __restrict__ in, unsigned short* __restrict__ hi,
               unsigned short* __restrict__ lo, int n4)
{
    int i = blockIdx.x * blockDim.x + threadIdx.x;
    const int stride = gridDim.x * blockDim.x;
    for (; i < n4; i += stride) {
        const float4 v = ((const float4*)in)[i];
        ushort4 h, l;
        h.x = f2bf(v.x); l.x = f2bf(v.x - bf2f(h.x));
        h.y = f2bf(v.y); l.y = f2bf(v.y - bf2f(h.y));
        h.z = f2bf(v.z); l.z = f2bf(v.z - bf2f(h.z));
        h.w = f2bf(v.w); l.w = f2bf(v.w - bf2f(h.w));
        ((ushort4*)hi)[i] = h;
        ((ushort4*)lo)[i] = l;
    }
}

// ---------------------------------------------------------------------------
// split_transpose: W[Wk][Wn] f32 -> hiT, loT [Wn][Wk] bf16; optional per-k
// scale (scale[k], e.g. LayerNorm gamma folded into the weight).
// grid = (Wn/32, Wk/32), block = 256.
// ---------------------------------------------------------------------------
__global__ __launch_bounds__(256)
void split_transpose(const float* __restrict__ W, unsigned short* __restrict__ hiT,
                     unsigned short* __restrict__ loT, int Wn, int Wk,
                     const float* __restrict__ scale)
{
    __shared__ float tile[32][33];
    const int c0 = blockIdx.x * 32;
    const int r0 = blockIdx.y * 32;
    const int t  = threadIdx.x;
    const int tr = t >> 3;            // 0..31
    const int tc = (t & 7) * 4;       // 0,4,...,28

    const float4 v = *(const float4*)(W + (size_t)(r0 + tr) * Wn + c0 + tc);
    tile[tr][tc + 0] = v.x; tile[tr][tc + 1] = v.y;
    tile[tr][tc + 2] = v.z; tile[tr][tc + 3] = v.w;
    __syncthreads();

    // output element j: hiT[(c0+tr)][r0+tc+j] = W[r0+tc+j][c0+tr], k = r0+tc+j
    float a0 = tile[tc + 0][tr];
    float a1 = tile[tc + 1][tr];
    float a2 = tile[tc + 2][tr];
    float a3 = tile[tc + 3][tr];
    if (scale) {
        a0 *= scale[r0 + tc + 0];
        a1 *= scale[r0 + tc + 1];
        a2 *= scale[r0 + tc + 2];
        a3 *= scale[r0 + tc + 3];
    }
    ushort4 h, l;
    h.x = f2bf(a0); l.x = f2bf(a0 - bf2f(h.x));
    h.y = f2bf(a1); l.y = f2bf(a1 - bf2f(h.y));
    h.z = f2bf(a2); l.z = f2bf(a2 - bf2f(h.z));
    h.w = f2bf(a3); l.w = f2bf(a3 - bf2f(h.w));
    *(ushort4*)(hiT + (size_t)(c0 + tr) * Wk + r0 + tc) = h;
    *(ushort4*)(loT + (size_t)(c0 + tr) * Wk + r0 + tc) = l;
}

// ---------------------------------------------------------------------------
// colsums: c1[n] = sum_k gamma[k]*W[k][n];  cc[n] = sum_k beta[k]*W[k][n] + bout[n]
// W = w_out [INNER][DIM].  grid = DIM/256 blocks.
// ---------------------------------------------------------------------------
__global__ __launch_bounds__(256)
void colsums(const float* __restrict__ W, const float* __restrict__ gamma,
             const float* __restrict__ beta, const float* __restrict__ bout,
             float* __restrict__ c1, float* __restrict__ cc)
{
    const int n = blockIdx.x * 256 + threadIdx.x;
    float s1 = 0.f, s2 = 0.f;
#pragma unroll 4
    for (int k = 0; k < INNER; ++k) {
        const float w = W[(size_t)k * DIM + n];
        s1 = fmaf(gamma[k], w, s1);
        s2 = fmaf(beta[k],  w, s2);
    }
    c1[n] = s1;
    cc[n] = s2 + bout[n];
}

// ---------------------------------------------------------------------------
// bf16x3 GEMM:  C = Ahi@Bhi + Ahi@Blo + Alo@Bhi  (fp32 accum)
// A*: [M][1024] bf16 row-major (M = gridDim.y*128 rows of this chunk).
// B*: [Ncols][1024] bf16 row-major (weight pre-transposed).
// 128x128 tile, BK=32, 4 waves (2x2 of 64x64), mfma_f32_16x16x32_bf16.
// Staging: classic reg-staged LDS (global->VGPR short8v loads issued BEFORE
// the consume-barrier, ds_write_b128 after) -- no global_load_lds this round
// (crash-hypothesis hedge; identical global access pattern + LDS layout).
// Single fused K-loop, all 4 panels (32KB LDS), 48 MFMA per barrier pair.
// Split destination: cols < 1024 -> C0[row*1024 + col]; cols >= 1024 ->
// C1[row*2048 + col-1024]  (EPI=0 only).  relu on cols < reluN.
// EPI=1: single dest C0 (stride 1024) with LN-affine epilogue:
//   out = rstd*acc - rstdmu*c1[col] + cc[col], stats[row]=(rstd, rstd*mu).
// XCD-chunked block swizzle (nwg % 8 == 0 required). [T1, m157/m192]
// ---------------------------------------------------------------------------
template<int EPI>
__global__ __launch_bounds__(256)
void gemm_bf16x3(const unsigned short* __restrict__ Ahi,
                 const unsigned short* __restrict__ Alo,
                 const unsigned short* __restrict__ Bhi,
                 const unsigned short* __restrict__ Blo,
                 const float* __restrict__ stats,
                 const float* __restrict__ c1,
                 const float* __restrict__ cc,
                 float* __restrict__ C0, float* __restrict__ C1, int reluN)
{
    __shared__ __align__(16) unsigned short As [128 * 32];  // Ahi [m][k] 8KB
    __shared__ __align__(16) unsigned short As2[128 * 32];  // Alo [m][k] 8KB
    __shared__ __align__(16) unsigned short Bs [128 * 32];  // Bhi [n][k] 8KB
    __shared__ __align__(16) unsigned short Bs2[128 * 32];  // Blo [n][k] 8KB

    // --- XCD-chunked swizzle (bijective when nwg % 8 == 0)
    const int nwg = gridDim.x * gridDim.y;
    int bid = blockIdx.y * gridDim.x + blockIdx.x;
    const int cpx = nwg >> 3;
    bid = (bid & 7) * cpx + (bid >> 3);
    const int col0 = (bid % gridDim.x) * 128;
    const int row0 = (bid / gridDim.x) * 128;

    const int t    = threadIdx.x;
    const int wid  = t >> 6;
    const int lane = t & 63;
    const int wr   = wid >> 1;              // wave row 0..1 (64 rows each)
    const int wc   = wid & 1;               // wave col 0..1
    const int lrow = lane & 15;             // fragment row/col
    const int lk8  = (lane >> 4) * 8;       // fragment k-offset (shorts)

    // staging map: thread t owns 16B at short-offset t*8 and 2048+t*8 of each
    // 128x32 panel; tile[m][k] -> row = off>>5, col = off&31.
    const int srow = t >> 2;                // 0..63
    const int scol = (t & 3) * 8;           // 0,8,16,24

    float4v acc[4][4];
#pragma unroll
    for (int i = 0; i < 4; ++i)
#pragma unroll
        for (int j = 0; j < 4; ++j)
            acc[i][j] = (float4v){0.f, 0.f, 0.f, 0.f};

    for (int kk0 = 0; kk0 < 1024; kk0 += 32) {
        // issue all 8 staging loads to VGPRs (in flight across the barrier)
        const size_t ga0 = (size_t)(row0 + srow) * 1024 + kk0 + scol;
        const size_t ga1 = (size_t)(row0 + 64 + srow) * 1024 + kk0 + scol;
        const size_t gb0 = (size_t)(col0 + srow) * 1024 + kk0 + scol;
        const size_t gb1 = (size_t)(col0 + 64 + srow) * 1024 + kk0 + scol;
        const short8v ra0 = *(const short8v*)(const void*)(Ahi + ga0);
        const short8v ra1 = *(const short8v*)(const void*)(Ahi + ga1);
        const short8v ra2 = *(const short8v*)(const void*)(Alo + ga0);
        const short8v ra3 = *(const short8v*)(const void*)(Alo + ga1);
        const short8v rb0 = *(const short8v*)(const void*)(Bhi + gb0);
        const short8v rb1 = *(const short8v*)(const void*)(Bhi + gb1);
        const short8v rb2 = *(const short8v*)(const void*)(Blo + gb0);
        const short8v rb3 = *(const short8v*)(const void*)(Blo + gb1);

        __syncthreads();   // prior tile fully consumed
        *(short8v*)(void*)&As [t * 8]        = ra0;
        *(short8v*)(void*)&As [2048 + t * 8] = ra1;
        *(short8v*)(void*)&As2[t * 8]        = ra2;
        *(short8v*)(void*)&As2[2048 + t * 8] = ra3;
        *(short8v*)(void*)&Bs [t * 8]        = rb0;
        *(short8v*)(void*)&Bs [2048 + t * 8] = rb1;
        *(short8v*)(void*)&Bs2[t * 8]        = rb2;
        *(short8v*)(void*)&Bs2[2048 + t * 8] = rb3;
        __syncthreads();   // tile visible to all waves

        // cluster 1: Ahi x Bhi, Ahi x Blo  (peak live: af+bf+bf2 = 48 VGPR)
        {
            short8v af[4], bf[4], bf2[4];
#pragma unroll
            for (int fm = 0; fm < 4; ++fm)
                af[fm] = *(const short8v*)(const void*)&As[(wr * 64 + fm * 16 + lrow) * 32 + lk8];
#pragma unroll
            for (int fn = 0; fn < 4; ++fn) {
                bf[fn]  = *(const short8v*)(const void*)&Bs [(wc * 64 + fn * 16 + lrow) * 32 + lk8];
                bf2[fn] = *(const short8v*)(const void*)&Bs2[(wc * 64 + fn * 16 + lrow) * 32 + lk8];
            }
#pragma unroll
            for (int fm = 0; fm < 4; ++fm)
#pragma unroll
                for (int fn = 0; fn < 4; ++fn)
                    acc[fm][fn] = __builtin_amdgcn_mfma_f32_16x16x32_bf16(
                        af[fm], bf[fn], acc[fm][fn], 0, 0, 0);
#pragma unroll
            for (int fm = 0; fm < 4; ++fm)
#pragma unroll
                for (int fn = 0; fn < 4; ++fn)
                    acc[fm][fn] = __builtin_amdgcn_mfma_f32_16x16x32_bf16(
                        af[fm], bf2[fn], acc[fm][fn], 0, 0, 0);

            // cluster 2: Alo x Bhi (af2 replaces bf2's registers; bf still live)
            short8v af2[4];
#pragma unroll
            for (int fm = 0; fm < 4; ++fm)
                af2[fm] = *(const short8v*)(const void*)&As2[(wr * 64 + fm * 16 + lrow) * 32 + lk8];
#pragma unroll
            for (int fm = 0; fm < 4; ++fm)
#pragma unroll
                for (int fn = 0; fn < 4; ++fn)
                    acc[fm][fn] = __builtin_amdgcn_mfma_f32_16x16x32_bf16(
                        af2[fm], bf[fn], acc[fm][fn], 0, 0, 0);
        }
    }

    // epilogue: D[row=(lane>>4)*4+r][col=lane&15] per fragment  [m89 layout]
    const int orow = (lane >> 4) * 4;

    float rs[4][4], rm[4][4];
    if constexpr (EPI == 1) {
#pragma unroll
        for (int fm = 0; fm < 4; ++fm)
#pragma unroll
            for (int r = 0; r < 4; ++r) {
                const int row = row0 + wr * 64 + fm * 16 + orow + r;
                rs[fm][r] = stats[row * 2 + 0];   // rstd
                rm[fm][r] = stats[row * 2 + 1];   // rstd*mu
            }
    }

    // destination select (block-uniform: 1024 % 128 == 0)
    const bool toC1   = (EPI == 0) && (col0 >= 1024);
    float* const Cd   = toC1 ? C1 : C0;
    const int cstride = toC1 ? 2048 : 1024;
    const int cofs    = toC1 ? 1024 : 0;
    const bool dorelu = (EPI == 0) && (col0 < reluN);

#pragma unroll
    for (int fn = 0; fn < 4; ++fn) {
        const int ccol = col0 + wc * 64 + fn * 16 + lrow;
        float c1v = 0.f, ccv = 0.f;
        if constexpr (EPI == 1) { c1v = c1[ccol]; ccv = cc[ccol]; }
#pragma unroll
        for (int fm = 0; fm < 4; ++fm) {
            const int rbase = row0 + wr * 64 + fm * 16 + orow;
#pragma unroll
            for (int r = 0; r < 4; ++r) {
                float v = acc[fm][fn][r];
                if constexpr (EPI == 1)
                    v = rs[fm][r] * v - rm[fm][r] * c1v + ccv;
                if (dorelu) v = fmaxf(v, 0.f);
                Cd[(size_t)(rbase + r) * cstride + (ccol - cofs)] = v;
            }
        }
    }
}

// ---------------------------------------------------------------------------
// kv accumulate over a chunk: kv[h][m][d] += sum_n k[n,h,m] * v[n,h,d]
// kvc = [RC][2048] (k local cols 0..1023, v local cols 1024..2047), k relu'd.
// grid = (16 heads, RC/512 segments), block = 256; atomics into kvb.
// ---------------------------------------------------------------------------
__global__ __launch_bounds__(256)
void kv_agg(const float* __restrict__ kvc, float* __restrict__ kvout)
{
    const int h   = blockIdx.x;          // 0..15
    const int seg = blockIdx.y;
    const int t   = threadIdx.x;
    const int tm  = t >> 4, td = t & 15;

    const int kcol = h * DHEAD;          // local k columns
    const int vcol = 1024 + h * DHEAD;   // local v columns

    __shared__ float Ks[32][68];
    __shared__ float Vs[32][68];

    float acc[4][4];
#pragma unroll
    for (int i = 0; i < 4; ++i)
#pragma unroll
        for (int j = 0; j < 4; ++j) acc[i][j] = 0.f;

    const int nn = t >> 4;
    const int cc = (t & 15) * 4;

    for (int c0 = 0; c0 < 512; c0 += 32) {
        const int n = seg * 512 + c0;
        const float* p0 = kvc + (size_t)(n + nn) * 2048;
        const float* p1 = kvc + (size_t)(n + nn + 16) * 2048;
        const float4 k0 = *(const float4*)(p0 + kcol + cc);
        const float4 k1 = *(const float4*)(p1 + kcol + cc);
        const float4 v0 = *(const float4*)(p0 + vcol + cc);
        const float4 v1 = *(const float4*)(p1 + vcol + cc);
        __syncthreads();
        *(float4*)&Ks[nn][cc]      = k0;
        *(float4*)&Ks[nn + 16][cc] = k1;
        *(float4*)&Vs[nn][cc]      = v0;
        *(float4*)&Vs[nn + 16][cc] = v1;
        __syncthreads();
#pragma unroll
        for (int i = 0; i < 32; ++i) {
            const float4 ka = *(const float4*)&Ks[i][tm * 4];
            const float4 vb = *(const float4*)&Vs[i][td * 4];
            acc[0][0] = fmaf(ka.x, vb.x, acc[0][0]);
            acc[0][1] = fmaf(ka.x, vb.y, acc[0][1]);
            acc[0][2] = fmaf(ka.x, vb.z, acc[0][2]);
            acc[0][3] = fmaf(ka.x, vb.w, acc[0][3]);
            acc[1][0] = fmaf(ka.y, vb.x, acc[1][0]);
            acc[1][1] = fmaf(ka.y, vb.y, acc[1][1]);
            acc[1][2] = fmaf(ka.y, vb.z, acc[1][2]);
            acc[1][3] = fmaf(ka.y, vb.w, acc[1][3]);
            acc[2][0] = fmaf(ka.z, vb.x, acc[2][0]);
            acc[2][1] = fmaf(ka.z, vb.y, acc[2][1]);
            acc[2][2] = fmaf(ka.z, vb.z, acc[2][2]);
            acc[2][3] = fmaf(ka.z, vb.w, acc[2][3]);
            acc[3][0] = fmaf(ka.w, vb.x, acc[3][0]);
            acc[3][1] = fmaf(ka.w, vb.y, acc[3][1]);
            acc[3][2] = fmaf(ka.w, vb.z, acc[3][2]);
            acc[3][3] = fmaf(ka.w, vb.w, acc[3][3]);
        }
    }

    float* outp = kvout + (size_t)h * DHEAD * DHEAD;
#pragma unroll
    for (int i = 0; i < 4; ++i)
#pragma unroll
        for (int j = 0; j < 4; ++j)
            atomicAdd(&outp[(tm * 4 + i) * DHEAD + td * 4 + j], acc[i][j]);
}

// ---------------------------------------------------------------------------
// Per chunk: o = q @ kv per head; writes o as bf16 hi/lo (unnormalized) into
// chunk-local buffers, plus per-row (rstd, rstd*mu).
// qc = q rows of this chunk, stride 1024.  grid = RC/64 blocks.
// ---------------------------------------------------------------------------
__global__ __launch_bounds__(256)
void o_stats_split(const float* __restrict__ qc, const float* __restrict__ kv,
                   unsigned short* __restrict__ oHi, unsigned short* __restrict__ oLo,
                   float* __restrict__ statsc)
{
    const int row0 = blockIdx.x * 64;    // chunk-local
    const int t    = threadIdx.x;
    const int rg   = t >> 4;             // 0..15 -> rows rg*4..+4
    const int dg   = t & 15;             // 0..15 -> cols dg*4..+4 (per head)

    __shared__ float Qs[64][68];
    __shared__ float KVs[64][68];

    float s[4]  = {0.f, 0.f, 0.f, 0.f};
    float ss[4] = {0.f, 0.f, 0.f, 0.f};

    const int lr = t >> 2;
    const int lc = (t & 3) * 16;

    for (int h = 0; h < HEADS; ++h) {
        const float* qbase = qc + (size_t)(row0 + lr) * 1024 + h * DHEAD + lc;
        const float4 q0 = *(const float4*)(qbase + 0);
        const float4 q1 = *(const float4*)(qbase + 4);
        const float4 q2 = *(const float4*)(qbase + 8);
        const float4 q3 = *(const float4*)(qbase + 12);
        const float* kvbase = kv + (size_t)(h * DHEAD + lr) * DHEAD + lc;
        const float4 c0 = *(const float4*)(kvbase + 0);
        const float4 c1 = *(const float4*)(kvbase + 4);
        const float4 c2 = *(const float4*)(kvbase + 8);
        const float4 c3 = *(const float4*)(kvbase + 12);
        __syncthreads();
        *(float4*)&Qs[lr][lc + 0]  = q0;
        *(float4*)&Qs[lr][lc + 4]  = q1;
        *(float4*)&Qs[lr][lc + 8]  = q2;
        *(float4*)&Qs[lr][lc + 12] = q3;
        *(float4*)&KVs[lr][lc + 0]  = c0;
        *(float4*)&KVs[lr][lc + 4]  = c1;
        *(float4*)&KVs[lr][lc + 8]  = c2;
        *(float4*)&KVs[lr][lc + 12] = c3;
        __syncthreads();

        float a[4][4];
#pragma unroll
        for (int i = 0; i < 4; ++i)
#pragma unroll
            for (int j = 0; j < 4; ++j) a[i][j] = 0.f;

#pragma unroll
        for (int m4 = 0; m4 < 16; ++m4) {
            float4 qa[4];
            qa[0] = *(const float4*)&Qs[rg * 4 + 0][m4 * 4];
            qa[1] = *(const float4*)&Qs[rg * 4 + 1][m4 * 4];
            qa[2] = *(const float4*)&Qs[rg * 4 + 2][m4 * 4];
            qa[3] = *(const float4*)&Qs[rg * 4 + 3][m4 * 4];
            const float4 v0 = *(const float4*)&KVs[m4 * 4 + 0][dg * 4];
            const float4 v1 = *(const float4*)&KVs[m4 * 4 + 1][dg * 4];
            const float4 v2 = *(const float4*)&KVs[m4 * 4 + 2][dg * 4];
            const float4 v3 = *(const float4*)&KVs[m4 * 4 + 3][dg * 4];
#pragma unroll
            for (int i = 0; i < 4; ++i) {
                a[i][0] = fmaf(qa[i].x, v0.x, a[i][0]);
                a[i][0] = fmaf(qa[i].y, v1.x, a[i][0]);
                a[i][0] = fmaf(qa[i].z, v2.x, a[i][0]);
                a[i][0] = fmaf(qa[i].w, v3.x, a[i][0]);
                a[i][1] = fmaf(qa[i].x, v0.y, a[i][1]);
                a[i][1] = fmaf(qa[i].y, v1.y, a[i][1]);
                a[i][1] = fmaf(qa[i].z, v2.y, a[i][1]);
                a[i][1] = fmaf(qa[i].w, v3.y, a[i][1]);
                a[i][2] = fmaf(qa[i].x, v0.z, a[i][2]);
                a[i][2] = fmaf(qa[i].y, v1.z, a[i][2]);
                a[i][2] = fmaf(qa[i].z, v2.z, a[i][2]);
                a[i][2] = fmaf(qa[i].w, v3.z, a[i][2]);
                a[i][3] = fmaf(qa[i].x, v0.w, a[i][3]);
                a[i][3] = fmaf(qa[i].y, v1.w, a[i][3]);
                a[i][3] = fmaf(qa[i].z, v2.w, a[i][3]);
                a[i][3] = fmaf(qa[i].w, v3.w, a[i][3]);
            }
        }

#pragma unroll
        for (int i = 0; i < 4; ++i) {
            const float4 w = make_float4(a[i][0], a[i][1], a[i][2], a[i][3]);
            ushort4 hh, ll;
            hh.x = f2bf(w.x); ll.x = f2bf(w.x - bf2f(hh.x));
            hh.y = f2bf(w.y); ll.y = f2bf(w.y - bf2f(hh.y));
            hh.z = f2bf(w.z); ll.z = f2bf(w.z - bf2f(hh.z));
            hh.w = f2bf(w.w); ll.w = f2bf(w.w - bf2f(hh.w));
            const size_t oidx = (size_t)(row0 + rg * 4 + i) * INNER + h * DHEAD + dg * 4;
            *(ushort4*)(oHi + oidx) = hh;
            *(ushort4*)(oLo + oidx) = ll;
            s[i]  += w.x + w.y + w.z + w.w;
            ss[i] += w.x * w.x + w.y * w.y + w.z * w.z + w.w * w.w;
        }
    }

#pragma unroll
    for (int i = 0; i < 4; ++i) {
        float si = s[i], qi = ss[i];
#pragma unroll
        for (int mask = 1; mask < 16; mask <<= 1) {
            si += __shfl_xor(si, mask);
            qi += __shfl_xor(qi, mask);
        }
        if (dg == 0) {
            const int r = row0 + rg * 4 + i;
            const float mean = si * (1.f / INNER);
            const float var  = qi * (1.f / INNER) - mean * mean;
            const float rstd = rsqrtf(var + EPS);
            statsc[r * 2 + 0] = rstd;
            statsc[r * 2 + 1] = rstd * mean;
        }
    }
}

// ---------------------------------------------------------------------------
extern "C" void kernel_launch(void* const* d_in, const int* in_sizes, int n_in,
                              void* d_out, int out_size, void* d_ws, size_t ws_size,
                              hipStream_t stream)
{
    const float* x     = (const float*)d_in[0];
    const float* w_qkv = (const float*)d_in[1];
    const float* gamma = (const float*)d_in[2];
    const float* beta  = (const float*)d_in[3];
    const float* w_out = (const float*)d_in[4];
    const float* b_out = (const float*)d_in[5];
    float* out = (float*)d_out;

    // ---- fixed workspace (~33.9 MB) ----
    char* ws = (char*)d_ws;
    size_t off = 0;
    unsigned short* hiWq = (unsigned short*)(ws + off); off += (size_t)QKVN * DIM * 2;
    unsigned short* loWq = (unsigned short*)(ws + off); off += (size_t)QKVN * DIM * 2;
    unsigned short* hiWo = (unsigned short*)(ws + off); off += (size_t)DIM * INNER * 2;
    unsigned short* loWo = (unsigned short*)(ws + off); off += (size_t)DIM * INNER * 2;
    float* c1v   = (float*)(ws + off);                  off += (size_t)DIM * 4;
    float* ccv   = (float*)(ws + off);                  off += (size_t)DIM * 4;
    float* qfull = (float*)(ws + off);                  off += (size_t)N_ * DIM * 4;   // q, per batch
    float* stats = (float*)(ws + off);                  off += (size_t)N_ * 2 * 4;
    float* kvb   = (float*)(ws + off);                  off += (size_t)HEADS * DHEAD * DHEAD * 4;

    // ---- chunk size: largest RC in {4096,2048,1024,512} fitting ws_size ----
    // per-chunk bytes: hiX/loX (RC*1024*2*2) + kvchunk (RC*2048*4) + oHi/oLo
    // (RC*1024*2*2) = RC*16384.
    int RC = 0;
    for (int cand = N_; cand >= 512; cand >>= 1)
        if (off + (size_t)cand * 16384 <= ws_size) { RC = cand; break; }
    if (RC == 0) return;  // ws too small: poisoned output, NO device fault

    unsigned short* hiX = (unsigned short*)(ws + off);  off += (size_t)RC * DIM * 2;
    unsigned short* loX = (unsigned short*)(ws + off);  off += (size_t)RC * DIM * 2;
    float* kvchunk = (float*)(ws + off);                off += (size_t)RC * 2048 * 4;
    unsigned short* oHi = (unsigned short*)(ws + off);  off += (size_t)RC * INNER * 2;
    unsigned short* oLo = (unsigned short*)(ws + off);  off += (size_t)RC * INNER * 2;

    // 0) weight splits (once): [N][K] layouts for contiguous staging;
    //    w_out gets gamma folded in; LN-affine column terms.
    split_transpose<<<dim3(QKVN / 32, DIM / 32), 256, 0, stream>>>(
        w_qkv, hiWq, loWq, QKVN, DIM, nullptr);
    split_transpose<<<dim3(DIM / 32, INNER / 32), 256, 0, stream>>>(
        w_out, hiWo, loWo, DIM, INNER, gamma);
    colsums<<<DIM / 256, 256, 0, stream>>>(w_out, gamma, beta, b_out, c1v, ccv);

    for (int b = 0; b < B_; ++b) {
        const float* xb   = x + (size_t)b * N_ * DIM;
        float*       outb = out + (size_t)b * N_ * DIM;

        hipMemsetAsync(kvb, 0, (size_t)HEADS * DHEAD * DHEAD * 4, stream);

        // pass 1: per chunk, qkv GEMM (q -> qfull, k|v -> kvchunk) + kv accumulate
        for (int cs = 0; cs < N_; cs += RC) {
            split_f32<<<2048, 256, 0, stream>>>(
                xb + (size_t)cs * DIM, hiX, loX, RC * DIM / 4);
            gemm_bf16x3<0><<<dim3(QKVN / 128, RC / 128), 256, 0, stream>>>(
                hiX, loX, hiWq, loWq, nullptr, nullptr, nullptr,
                qfull + (size_t)cs * DIM, kvchunk, 2 * INNER);
            kv_agg<<<dim3(HEADS, RC / 512), 256, 0, stream>>>(kvchunk, kvb);
        }

        // pass 2: per chunk, o = q@kv (bf16 hi/lo + LN stats), then GEMM2
        for (int cs = 0; cs < N_; cs += RC) {
            o_stats_split<<<dim3(RC / 64), 256, 0, stream>>>(
                qfull + (size_t)cs * DIM, kvb, oHi, oLo, stats + (size_t)cs * 2);
            gemm_bf16x3<1><<<dim3(DIM / 128, RC / 128), 256, 0, stream>>>(
                oHi, oLo, hiWo, loWo, stats + (size_t)cs * 2, c1v, ccv,
                outb + (size_t)cs * DIM, nullptr, 0);
        }
    }
}